// Round 7
// baseline (447.204 us; speedup 1.0000x reference)
//
#include <hip/hip_runtime.h>
#include <hip/hip_cooperative_groups.h>
#include <stdint.h>

namespace cg = cooperative_groups;
typedef unsigned int uint32;

// ReviewLoss: ce[i] = logsumexp(out[i,:]) - out[i, target[i]]
//   lam = k-th (0-indexed, descending) order statistic of ce, k = int(N*0.3)
//   result = mean over ALL N of (ce >= lam ? ce : 0)
//
// R6 post-mortem: 5 serialized dispatches + single-CU selector = ~50us of
// scheduling overhead on ~40us of work. This round: ONE cooperative kernel.
//   Phase A: zero ws + ce (16 rows/wave, software-pipelined loads) +
//            per-block packed 16384-bin LDS hist (key = u>>17, 14 bits for
//            ce>=0) + ce stashed in LDS (no global ce array at all).
//   sync -> Phase B: flush LDS hist to 8 global replicas (no hot words).
//   sync -> Phase C: block 0 merges replicas, suffix-scans -> (K, kr1).
//   sync -> Phase D: every block, wave 0: partial sum of (key>K) from the
//            LDS stash + ballot-aggregated candidate (key==K) append into
//            8 sharded segments (seg = bid&7, <=64 blocks x 64 rows = 4096
//            entries max -> never overflows).
//   sync -> Phase E: block 0: exact lambda via level-2 (bits 16..3) +
//            level-3 (bits 2..0) hists over candidates; reduce partials +
//            candidate tail; write mean.

#define TPB 256
#define ROWS_PER_BLK 64
#define ROWS_PER_WAVE 16
#define HWORDS 8192   // 16384 packed u16 bins
#define NREP 8
#define SEGCAP 4096

// Find descending-rank `rank` in packed 16384-bin hist H (8192 words),
// 256 threads. g[256] scratch. Out: sel[0]=bin, sel[1]=rank-within-bin.
__device__ void find_level_256(uint32* H, uint32* g, uint32 rank, int tid,
                               volatile uint32* sel) {
  uint32 c = 0;
#pragma unroll 8
  for (int j = 0; j < 32; ++j) {
    uint32 w = H[32 * tid + j];
    c += (w & 0xFFFFu) + (w >> 16);
  }
  g[tid] = c;
  __syncthreads();
  for (int off = 1; off < 256; off <<= 1) {  // inclusive suffix scan
    uint32 v = g[tid] + ((tid + off < 256) ? g[tid + off] : 0u);
    __syncthreads();
    g[tid] = v;
    __syncthreads();
  }
  uint32 SG = (tid + 1 < 256) ? g[tid + 1] : 0u;
  if (SG <= rank && rank < g[tid]) { sel[0] = (uint32)tid; sel[1] = rank - SG; }
  __syncthreads();
  if (tid == 0) {
    uint32 grp = sel[0], kg = sel[1], acc = 0;
    for (int b = 63; b >= 0; --b) {
      uint32 bin = grp * 64u + (uint32)b;
      uint32 w = H[bin >> 1];
      uint32 cc = (bin & 1u) ? (w >> 16) : (w & 0xFFFFu);
      if (kg < acc + cc) { sel[0] = bin; sel[1] = kg - acc; break; }
      acc += cc;
    }
  }
  __syncthreads();
}

__global__ __launch_bounds__(TPB, 4) void review_loss_kernel(
    const float* __restrict__ logits, const int* __restrict__ target,
    uint32* __restrict__ rep,      // NREP * HWORDS
    uint32* __restrict__ cand,     // NREP * SEGCAP
    uint32* __restrict__ ccnt,     // NREP counters
    uint32* __restrict__ kkr,      // K, kr1
    double* __restrict__ partials, // gridDim.x
    float* __restrict__ out, int N, int C, int k) {
  cg::grid_group grid = cg::this_grid();
  __shared__ uint32 H[HWORDS];          // 32 KB
  __shared__ float stash[ROWS_PER_BLK];
  __shared__ uint32 g[256];
  __shared__ uint32 sel[2];
  __shared__ uint32 cnt8[8];
  __shared__ double wsum[4];

  const int tid = (int)threadIdx.x;
  const int lane = tid & 63;
  const int wid = tid >> 6;
  const int bid = (int)blockIdx.x;
  const int nblk = (int)gridDim.x;

  // ---- Phase A0: zero global scratch (grid-strided) + LDS hist ----
  for (int j = bid * TPB + tid; j < NREP * HWORDS; j += nblk * TPB) rep[j] = 0;
  if (bid == 0 && tid < NREP) ccnt[tid] = 0;
  for (int j = tid; j < HWORDS; j += TPB) H[j] = 0;
  __syncthreads();

  // ---- Phase A1: CE, 16 rows per wave, next-row loads pipelined ----
  const int nv4 = C >> 2;  // C % 4 == 0 (C=1000 -> 250 quads)
  const float4 NEG = make_float4(-INFINITY, -INFINITY, -INFINITY, -INFINITY);
  const int rbase = bid * ROWS_PER_BLK + wid * ROWS_PER_WAVE;
  const float4* rp4 = (const float4*)(logits + (size_t)rbase * (size_t)C);

  float4 a0 = (lane       < nv4) ? rp4[lane      ] : NEG;
  float4 a1 = (lane +  64 < nv4) ? rp4[lane +  64] : NEG;
  float4 a2 = (lane + 128 < nv4) ? rp4[lane + 128] : NEG;
  float4 a3 = (lane + 192 < nv4) ? rp4[lane + 192] : NEG;
  int t_next = (rbase < N) ? target[rbase] : 0;

  for (int r = 0; r < ROWS_PER_WAVE; ++r) {
    const int row = rbase + r;
    if (row >= N) break;  // wave-uniform (N % 64 == 0 in practice)
    float4 v0 = a0, v1 = a1, v2 = a2, v3 = a3;
    const int t = t_next;
    const float ot = ((const float*)rp4)[t];
    if (r + 1 < ROWS_PER_WAVE && row + 1 < N) {
      const float4* np4 = rp4 + nv4;
      a0 = (lane       < nv4) ? np4[lane      ] : NEG;
      a1 = (lane +  64 < nv4) ? np4[lane +  64] : NEG;
      a2 = (lane + 128 < nv4) ? np4[lane + 128] : NEG;
      a3 = (lane + 192 < nv4) ? np4[lane + 192] : NEG;
      t_next = target[row + 1];
    }
    float m = fmaxf(fmaxf(fmaxf(v0.x, v0.y), fmaxf(v0.z, v0.w)),
                    fmaxf(fmaxf(fmaxf(v1.x, v1.y), fmaxf(v1.z, v1.w)),
                          fmaxf(fmaxf(fmaxf(v2.x, v2.y), fmaxf(v2.z, v2.w)),
                                fmaxf(fmaxf(v3.x, v3.y), fmaxf(v3.z, v3.w)))));
#pragma unroll
    for (int off = 1; off < 64; off <<= 1) m = fmaxf(m, __shfl_xor(m, off));

    float e = __expf(v0.x - m) + __expf(v0.y - m) + __expf(v0.z - m) + __expf(v0.w - m)
            + __expf(v1.x - m) + __expf(v1.y - m) + __expf(v1.z - m) + __expf(v1.w - m)
            + __expf(v2.x - m) + __expf(v2.y - m) + __expf(v2.z - m) + __expf(v2.w - m)
            + __expf(v3.x - m) + __expf(v3.y - m) + __expf(v3.z - m) + __expf(v3.w - m);
#pragma unroll
    for (int off = 1; off < 64; off <<= 1) e += __shfl_xor(e, off);

    if (lane == 0) {
      float cev = fmaxf((m - ot) + __logf(e), 0.0f);  // ce >= 0; kill -0.0
      stash[wid * ROWS_PER_WAVE + r] = cev;
      uint32 key = __float_as_uint(cev) >> 17;  // <= 16320 < 16384
      atomicAdd(&H[key >> 1], (key & 1u) ? 0x10000u : 1u);
    }
    rp4 += nv4;
  }
  __syncthreads();
  grid.sync();  // (1) zeros done everywhere; all LDS hists complete

  // ---- Phase B: flush LDS hist to replica (bid & 7) ----
  {
    uint32* R = rep + (size_t)(bid & 7) * HWORDS;
    for (int j = tid; j < HWORDS; j += TPB) {
      uint32 w = H[j];
      if (w) atomicAdd(&R[j], w);
    }
  }
  grid.sync();  // (2) replicas complete

  // ---- Phase C: block 0 merges replicas + level-1 select ----
  if (bid == 0) {
    for (int j = tid; j < HWORDS; j += TPB) {
      uint32 w = 0;
#pragma unroll
      for (int r = 0; r < NREP; ++r) w += rep[(size_t)r * HWORDS + j];
      H[j] = w;  // own per-block hist no longer needed
    }
    __syncthreads();
    find_level_256(H, g, (uint32)k, tid, sel);
    if (tid == 0) { kkr[0] = sel[0]; kkr[1] = sel[1]; }
  }
  grid.sync();  // (3) K, kr1 visible

  const uint32 K = kkr[0];

  // ---- Phase D: wave 0 of each block: partial sum + candidate collect ----
  if (wid == 0) {
    const int myrow = bid * ROWS_PER_BLK + lane;
    const bool valid = (myrow < N);
    const float v = valid ? stash[lane] : 0.0f;
    const uint32 u = __float_as_uint(v);
    const uint32 key = u >> 17;
    double p = (valid && key > K) ? (double)v : 0.0;
#pragma unroll
    for (int off = 1; off < 64; off <<= 1) p += __shfl_xor(p, off);
    if (lane == 0) partials[bid] = p;

    const bool mine = valid && (key == K);
    unsigned long long mk = __ballot(mine);
    if (mk) {
      int src = (int)__ffsll(mk) - 1;
      uint32 base = 0;
      if (lane == src) base = atomicAdd(&ccnt[bid & 7], (uint32)__popcll(mk));
      base = (uint32)__shfl((int)base, src);
      if (mine) {
        uint32 pos = base + (uint32)__popcll(mk & ((1ull << lane) - 1ull));
        cand[(size_t)(bid & 7) * SEGCAP + pos] = u;  // pos < 4096 guaranteed
      }
    }
  }
  grid.sync();  // (4) partials + candidates complete

  // ---- Phase E: block 0: resolve exact lambda + final sum ----
  if (bid == 0) {
    const uint32 kr1 = kkr[1];
    // level-2: hist over candidate bits 16..3 (14 bits)
    for (int j = tid; j < HWORDS; j += TPB) H[j] = 0;
    if (tid < 8) cnt8[tid] = 0;
    __syncthreads();
    for (int s = 0; s < NREP; ++s) {
      const uint32 cs = ccnt[s];
      for (uint32 j = (uint32)tid; j < cs; j += TPB) {
        uint32 u = cand[(size_t)s * SEGCAP + j];
        uint32 k2 = (u >> 3) & 0x3FFFu;
        atomicAdd(&H[k2 >> 1], (k2 & 1u) ? 0x10000u : 1u);
      }
    }
    __syncthreads();
    find_level_256(H, g, kr1, tid, sel);
    const uint32 B2 = sel[0];
    const uint32 kr2 = sel[1];
    __syncthreads();

    // level-3: 8 bins over bits 2..0
    const uint32 pre = (K << 14) | B2;  // = lam >> 3
    for (int s = 0; s < NREP; ++s) {
      const uint32 cs = ccnt[s];
      for (uint32 j = (uint32)tid; j < cs; j += TPB) {
        uint32 u = cand[(size_t)s * SEGCAP + j];
        if ((u >> 3) == pre) atomicAdd(&cnt8[u & 7u], 1u);
      }
    }
    __syncthreads();
    if (tid == 0) {
      uint32 kg = kr2, acc = 0;
      for (int b = 7; b >= 0; --b) {
        uint32 cc = cnt8[b];
        if (kg < acc + cc) { sel[0] = (pre << 3) | (uint32)b; break; }
        acc += cc;
      }
    }
    __syncthreads();
    const uint32 lam = sel[0];

    // final sum: partials + candidates >= lam (ties kept, matches ref)
    double acc = 0.0;
    for (int j = tid; j < nblk; j += TPB) acc += partials[j];
    for (int s = 0; s < NREP; ++s) {
      const uint32 cs = ccnt[s];
      for (uint32 j = (uint32)tid; j < cs; j += TPB) {
        uint32 u = cand[(size_t)s * SEGCAP + j];
        if (u >= lam) acc += (double)__uint_as_float(u);
      }
    }
#pragma unroll
    for (int off = 1; off < 64; off <<= 1) acc += __shfl_xor(acc, off);
    if (lane == 0) wsum[wid] = acc;
    __syncthreads();
    if (tid == 0) {
      double tsum = wsum[0] + wsum[1] + wsum[2] + wsum[3];
      out[0] = (float)(tsum / (double)N);
    }
  }
}

extern "C" void kernel_launch(void* const* d_in, const int* in_sizes, int n_in,
                              void* d_out, int out_size, void* d_ws, size_t ws_size,
                              hipStream_t stream) {
  const float* logits = (const float*)d_in[0];
  const int* target = (const int*)d_in[1];
  float* out = (float*)d_out;

  int N = in_sizes[1];            // 32768
  int C = in_sizes[0] / N;        // 1000
  int k = (int)((double)N * 0.3); // 9830

  // ws layout
  char* p = (char*)d_ws;
  uint32* rep = (uint32*)p;                       p += (size_t)NREP * HWORDS * 4;  // 256 KB
  uint32* cand = (uint32*)p;                      p += (size_t)NREP * SEGCAP * 4;  // 128 KB
  uint32* ccnt = (uint32*)p;                      p += 64;
  uint32* kkr = (uint32*)p;                       p += 64;   // keep 8B-align below
  double* partials = (double*)p;

  int nblk = (N + ROWS_PER_BLK - 1) / ROWS_PER_BLK;  // 512

  void* args[] = {(void*)&logits, (void*)&target, (void*)&rep, (void*)&cand,
                  (void*)&ccnt, (void*)&kkr, (void*)&partials, (void*)&out,
                  (void*)&N, (void*)&C, (void*)&k};
  hipLaunchCooperativeKernel((const void*)review_loss_kernel, dim3(nblk),
                             dim3(TPB), args, 0, stream);
}

// Round 9
// 196.740 us; speedup vs baseline: 2.2731x; 2.2731x over previous
//
#include <hip/hip_runtime.h>
#include <stdint.h>

// ReviewLoss: ce[i] = logsumexp(out[i,:]) - out[i, target[i]]
//   lam = k-th (0-indexed, descending) order statistic of ce, k = int(N*0.3)
//   result = mean over ALL N of (ce >= lam ? ce : 0)
//
// R8: compile fix only — __builtin_nontemporal_load needs a NATIVE vector
// type (ext_vector_type), not HIP_vector_type<float,4>. Theory unchanged
// from R7: streaming ce (4 rows/wave, 1-row-ahead software pipeline) +
// nontemporal loads. Signature: FETCH_SIZE ~131MB => nt worked; ~65MB =>
// structure did.

typedef unsigned int uint32;
typedef float vfloat4 __attribute__((ext_vector_type(4)));

#define LDNT(p) __builtin_nontemporal_load(p)

__device__ __forceinline__ float reduce_ce(vfloat4 v0, vfloat4 v1, vfloat4 v2,
                                           vfloat4 v3, float ot) {
  float m = fmaxf(fmaxf(fmaxf(v0.x, v0.y), fmaxf(v0.z, v0.w)),
                  fmaxf(fmaxf(fmaxf(v1.x, v1.y), fmaxf(v1.z, v1.w)),
                        fmaxf(fmaxf(fmaxf(v2.x, v2.y), fmaxf(v2.z, v2.w)),
                              fmaxf(fmaxf(v3.x, v3.y), fmaxf(v3.z, v3.w)))));
#pragma unroll
  for (int off = 1; off < 64; off <<= 1) m = fmaxf(m, __shfl_xor(m, off));
  float e = __expf(v0.x - m) + __expf(v0.y - m) + __expf(v0.z - m) + __expf(v0.w - m)
          + __expf(v1.x - m) + __expf(v1.y - m) + __expf(v1.z - m) + __expf(v1.w - m)
          + __expf(v2.x - m) + __expf(v2.y - m) + __expf(v2.z - m) + __expf(v2.w - m)
          + __expf(v3.x - m) + __expf(v3.y - m) + __expf(v3.z - m) + __expf(v3.w - m);
#pragma unroll
  for (int off = 1; off < 64; off <<= 1) e += __shfl_xor(e, off);
  return fmaxf((m - ot) + __logf(e), 0.0f);  // ce >= 0; kill -0.0
}

// 4 rows per wave, one-row-ahead pipeline. No LDS, no barriers.
__global__ __launch_bounds__(256) void ce_kernel(
    const float* __restrict__ logits, const int* __restrict__ target,
    float* __restrict__ ce, int N, int C) {
  const int lane = (int)(threadIdx.x & 63);
  const int wave = (int)((blockIdx.x * blockDim.x + threadIdx.x) >> 6);
  const int r0 = wave * 4;
  if (r0 >= N) return;

  const int nv4 = C >> 2;  // C % 4 == 0 (C=1000 -> 250 quads)
  const vfloat4 NEG = {-INFINITY, -INFINITY, -INFINITY, -INFINITY};
  const vfloat4* p0 = (const vfloat4*)(logits + (size_t)r0 * (size_t)C);

#define LOADQ(d0, d1, d2, d3, bp)                          \
  d0 = (lane       < nv4) ? LDNT((bp) + lane      ) : NEG; \
  d1 = (lane +  64 < nv4) ? LDNT((bp) + lane +  64) : NEG; \
  d2 = (lane + 128 < nv4) ? LDNT((bp) + lane + 128) : NEG; \
  d3 = (lane + 192 < nv4) ? LDNT((bp) + lane + 192) : NEG;

  vfloat4 a0, a1, a2, a3, b0, b1, b2, b3;

  // prime: row r0
  LOADQ(a0, a1, a2, a3, p0);
  int ta = target[r0];
  float ota = ((const float*)p0)[ta];

  // row r0: prefetch r0+1, reduce a
  bool has1 = (r0 + 1 < N);
  const vfloat4* p1 = p0 + nv4;
  if (has1) { LOADQ(b0, b1, b2, b3, p1); }
  int tb = has1 ? target[r0 + 1] : 0;
  float otb = has1 ? ((const float*)p1)[tb] : 0.0f;
  {
    float cev = reduce_ce(a0, a1, a2, a3, ota);
    if (lane == 0) ce[r0] = cev;
  }
  if (!has1) return;

  // row r0+1: prefetch r0+2 into a, reduce b
  bool has2 = (r0 + 2 < N);
  const vfloat4* p2 = p1 + nv4;
  if (has2) { LOADQ(a0, a1, a2, a3, p2); }
  ta = has2 ? target[r0 + 2] : 0;
  ota = has2 ? ((const float*)p2)[ta] : 0.0f;
  {
    float cev = reduce_ce(b0, b1, b2, b3, otb);
    if (lane == 0) ce[r0 + 1] = cev;
  }
  if (!has2) return;

  // row r0+2: prefetch r0+3 into b, reduce a
  bool has3 = (r0 + 3 < N);
  const vfloat4* p3 = p2 + nv4;
  if (has3) { LOADQ(b0, b1, b2, b3, p3); }
  tb = has3 ? target[r0 + 3] : 0;
  otb = has3 ? ((const float*)p3)[tb] : 0.0f;
  {
    float cev = reduce_ce(a0, a1, a2, a3, ota);
    if (lane == 0) ce[r0 + 2] = cev;
  }
  if (!has3) return;

  // row r0+3: reduce b
  {
    float cev = reduce_ce(b0, b1, b2, b3, otb);
    if (lane == 0) ce[r0 + 3] = cev;
  }
#undef LOADQ
}

// ---------------- selection + filtered mean (single block) ----------------

// Find descending-rank `rank` in packed 16384-bin hist H (8192 words),
// 1024 threads, g[1024] scratch. Out: sel[0]=bin, sel[1]=rank-within-bin.
__device__ void find_level_1024(uint32* H, uint32* g, uint32 rank, int tid,
                                volatile uint32* sel) {
  uint32 c = 0;
#pragma unroll
  for (int j = 0; j < 8; ++j) {
    uint32 w = H[8 * tid + j];
    c += (w & 0xFFFFu) + (w >> 16);
  }
  g[tid] = c;
  __syncthreads();
  for (int off = 1; off < 1024; off <<= 1) {  // inclusive suffix scan
    uint32 v = g[tid] + ((tid + off < 1024) ? g[tid + off] : 0u);
    __syncthreads();
    g[tid] = v;
    __syncthreads();
  }
  uint32 SG = (tid + 1 < 1024) ? g[tid + 1] : 0u;
  if (SG <= rank && rank < g[tid]) { sel[0] = (uint32)tid; sel[1] = rank - SG; }
  __syncthreads();
  if (tid == 0) {
    uint32 grp = sel[0], kg = sel[1], acc = 0;
    for (int b = 15; b >= 0; --b) {
      uint32 bin = grp * 16u + (uint32)b;
      uint32 w = H[bin >> 1];
      uint32 cc = (bin & 1u) ? (w >> 16) : (w & 0xFFFFu);
      if (kg < acc + cc) { sel[0] = bin; sel[1] = kg - acc; break; }
      acc += cc;
    }
  }
  __syncthreads();
}

__global__ __launch_bounds__(1024) void select_kernel(
    const float* __restrict__ ce, float* __restrict__ out, int N, int k) {
  __shared__ uint32 H[8192];     // packed 16384-bin hist (reused level 2)
  __shared__ uint32 Cand[8192];  // candidate bit patterns
  __shared__ uint32 g[1024];
  __shared__ uint32 sel[2];
  __shared__ uint32 ccnt;
  __shared__ uint32 cnt8[8];
  __shared__ double wsum[16];
  const int tid = (int)threadIdx.x;
  const int lane = tid & 63;
  const float4* ce4 = (const float4*)ce;
  const int N4 = N >> 2;  // N % 4 == 0

  if (tid == 0) ccnt = 0;
  if (tid < 8) cnt8[tid] = 0;
  for (int j = tid; j < 8192; j += 1024) H[j] = 0;
  __syncthreads();

  // ---- Pass 1: 16384-bin hist of key = u >> 17 (ce >= 0 -> key <= 16320) ----
  for (int i = tid; i < N4; i += 1024) {
    float4 x = ce4[i];
    uint32 k0 = __float_as_uint(x.x) >> 17;
    uint32 k1 = __float_as_uint(x.y) >> 17;
    uint32 k2 = __float_as_uint(x.z) >> 17;
    uint32 k3 = __float_as_uint(x.w) >> 17;
    atomicAdd(&H[k0 >> 1], (k0 & 1u) ? 0x10000u : 1u);
    atomicAdd(&H[k1 >> 1], (k1 & 1u) ? 0x10000u : 1u);
    atomicAdd(&H[k2 >> 1], (k2 & 1u) ? 0x10000u : 1u);
    atomicAdd(&H[k3 >> 1], (k3 & 1u) ? 0x10000u : 1u);
  }
  __syncthreads();
  find_level_1024(H, g, (uint32)k, tid, sel);
  const uint32 K = sel[0];
  const uint32 kr1 = sel[1];
  __syncthreads();

  // ---- Pass 2: sum key > K; ballot-collect key == K candidates ----
  double acc = 0.0;
  const int iters = (N4 + 1023) / 1024;
  for (int it = 0; it < iters; ++it) {   // uniform trip count for ballots
    int i = it * 1024 + tid;
    bool valid = (i < N4);
    float4 x = make_float4(0.f, 0.f, 0.f, 0.f);
    if (valid) x = ce4[i];
    float f[4] = {x.x, x.y, x.z, x.w};
#pragma unroll
    for (int j = 0; j < 4; ++j) {
      uint32 u = __float_as_uint(f[j]);
      uint32 key = u >> 17;
      if (valid && key > K) acc += (double)f[j];
      bool mine = valid && (key == K);
      unsigned long long mk = __ballot(mine);
      if (mk) {
        int src = (int)__ffsll(mk) - 1;
        uint32 base = 0;
        if (lane == src) base = atomicAdd(&ccnt, (uint32)__popcll(mk));
        base = (uint32)__shfl((int)base, src);
        if (mine) {
          uint32 p = base + (uint32)__popcll(mk & ((1ull << lane) - 1ull));
          if (p < 8192u) Cand[p] = u;
        }
      }
    }
  }
  __syncthreads();
  const uint32 c = (ccnt < 8192u) ? ccnt : 8192u;

  // ---- Level 2: hist over candidate bits 16..3 (14 bits) ----
  for (int j = tid; j < 8192; j += 1024) H[j] = 0;
  __syncthreads();
  for (uint32 j = (uint32)tid; j < c; j += 1024u) {
    uint32 k2 = (Cand[j] >> 3) & 0x3FFFu;
    atomicAdd(&H[k2 >> 1], (k2 & 1u) ? 0x10000u : 1u);
  }
  __syncthreads();
  find_level_1024(H, g, kr1, tid, sel);
  const uint32 B2 = sel[0];
  const uint32 kr2 = sel[1];
  __syncthreads();

  const uint32 lam_hi = (K << 17) | (B2 << 3);

  // ---- Level 3: 8 bins over bits 2..0 ----
  for (uint32 j = (uint32)tid; j < c; j += 1024u) {
    uint32 u = Cand[j];
    if ((u >> 3) == (lam_hi >> 3)) atomicAdd(&cnt8[u & 7u], 1u);
  }
  __syncthreads();
  if (tid == 0) {
    uint32 kg = kr2, a2 = 0;
    for (int b = 7; b >= 0; --b) {
      uint32 cc = cnt8[b];
      if (kg < a2 + cc) { sel[0] = lam_hi | (uint32)b; break; }
      a2 += cc;
    }
  }
  __syncthreads();
  const uint32 lam = sel[0];

  // ---- Add candidates >= lam (ties kept: matches where(ce<lam,0,ce)) ----
  for (uint32 j = (uint32)tid; j < c; j += 1024u) {
    uint32 u = Cand[j];
    if (u >= lam) acc += (double)__uint_as_float(u);
  }

  // ---- Reduce and write mean over all N ----
#pragma unroll
  for (int off = 1; off < 64; off <<= 1) acc += __shfl_xor(acc, off);
  if ((tid & 63) == 0) wsum[tid >> 6] = acc;
  __syncthreads();
  if (tid == 0) {
    double tsum = 0.0;
    for (int i = 0; i < 16; ++i) tsum += wsum[i];
    out[0] = (float)(tsum / (double)N);
  }
}

extern "C" void kernel_launch(void* const* d_in, const int* in_sizes, int n_in,
                              void* d_out, int out_size, void* d_ws, size_t ws_size,
                              hipStream_t stream) {
  const float* logits = (const float*)d_in[0];
  const int* target = (const int*)d_in[1];
  float* out = (float*)d_out;

  const int N = in_sizes[1];            // 32768
  const int C = in_sizes[0] / N;        // 1000
  const int k = (int)((double)N * 0.3); // 9830

  float* ce = (float*)d_ws;

  // K1: 4 rows per wave, 16 rows per 256-thread block.
  int nblk = (N + 15) / 16;  // 2048
  ce_kernel<<<nblk, 256, 0, stream>>>(logits, target, ce, N, C);

  // K2: single block: hist + select + filtered mean. No memset needed.
  select_kernel<<<1, 1024, 0, stream>>>(ce, out, N, k);
}

// Round 10
// 194.482 us; speedup vs baseline: 2.2995x; 1.0116x over previous
//
#include <hip/hip_runtime.h>
#include <stdint.h>

// ReviewLoss: ce[i] = logsumexp(out[i,:]) - out[i, target[i]]
//   lam = k-th (0-indexed, descending) order statistic of ce, k = int(N*0.3)
//   result = mean over ALL N of (ce >= lam ? ce : 0)
//
// R9 post-mortem: streaming ce + nt loads won 17us (total 196.7). ce is
// still ~53us vs 21us roofline. Remaining serial term: per-row
// target[row] -> rp[t] is a DEPENDENT 2-deep global chain (~1800cy) that
// gates each reduce. Fix: the row is already in registers — extract
// ot = row[t] via uniform selects + one __shfl from the owning lane
// (t is wave-uniform). target[] loads hoisted to kernel entry.

typedef unsigned int uint32;
typedef float vfloat4 __attribute__((ext_vector_type(4)));

#define LDNT(p) __builtin_nontemporal_load(p)

__device__ __forceinline__ float reduce_ce(vfloat4 v0, vfloat4 v1, vfloat4 v2,
                                           vfloat4 v3, float ot) {
  float m = fmaxf(fmaxf(fmaxf(v0.x, v0.y), fmaxf(v0.z, v0.w)),
                  fmaxf(fmaxf(fmaxf(v1.x, v1.y), fmaxf(v1.z, v1.w)),
                        fmaxf(fmaxf(fmaxf(v2.x, v2.y), fmaxf(v2.z, v2.w)),
                              fmaxf(fmaxf(v3.x, v3.y), fmaxf(v3.z, v3.w)))));
#pragma unroll
  for (int off = 1; off < 64; off <<= 1) m = fmaxf(m, __shfl_xor(m, off));
  float e = __expf(v0.x - m) + __expf(v0.y - m) + __expf(v0.z - m) + __expf(v0.w - m)
          + __expf(v1.x - m) + __expf(v1.y - m) + __expf(v1.z - m) + __expf(v1.w - m)
          + __expf(v2.x - m) + __expf(v2.y - m) + __expf(v2.z - m) + __expf(v2.w - m)
          + __expf(v3.x - m) + __expf(v3.y - m) + __expf(v3.z - m) + __expf(v3.w - m);
#pragma unroll
  for (int off = 1; off < 64; off <<= 1) e += __shfl_xor(e, off);
  return fmaxf((m - ot) + __logf(e), 0.0f);  // ce >= 0; kill -0.0
}

// Extract row[t] from the distributed register image. t is wave-uniform:
// quad q = t>>2 lives in set q>>6 of lane q&63, component t&3.
__device__ __forceinline__ float extract_elem(vfloat4 v0, vfloat4 v1,
                                              vfloat4 v2, vfloat4 v3, int t) {
  const int q = t >> 2;
  const int comp = t & 3;
  const int set = q >> 6;
  const int src = q & 63;
  vfloat4 v = (set == 0) ? v0 : (set == 1) ? v1 : (set == 2) ? v2 : v3;
  float val = (comp == 0) ? v.x : (comp == 1) ? v.y : (comp == 2) ? v.z : v.w;
  return __shfl(val, src);
}

// 4 rows per wave, one-row-ahead pipeline. No LDS, no barriers, no
// dependent global loads (ot comes from registers).
__global__ __launch_bounds__(256) void ce_kernel(
    const float* __restrict__ logits, const int* __restrict__ target,
    float* __restrict__ ce, int N, int C) {
  const int lane = (int)(threadIdx.x & 63);
  const int wave = (int)((blockIdx.x * blockDim.x + threadIdx.x) >> 6);
  const int r0 = wave * 4;
  if (r0 >= N) return;

  const int nv4 = C >> 2;  // C % 4 == 0 (C=1000 -> 250 quads)
  const vfloat4 NEG = {-INFINITY, -INFINITY, -INFINITY, -INFINITY};
  const vfloat4* p0 = (const vfloat4*)(logits + (size_t)r0 * (size_t)C);

  const bool has1 = (r0 + 1 < N);
  const bool has2 = (r0 + 2 < N);
  const bool has3 = (r0 + 3 < N);

  // Hoisted target loads (independent, issued with the first LOADQ).
  const int t0 = target[r0];
  const int t1 = has1 ? target[r0 + 1] : 0;
  const int t2 = has2 ? target[r0 + 2] : 0;
  const int t3 = has3 ? target[r0 + 3] : 0;

#define LOADQ(d0, d1, d2, d3, bp)                          \
  d0 = (lane       < nv4) ? LDNT((bp) + lane      ) : NEG; \
  d1 = (lane +  64 < nv4) ? LDNT((bp) + lane +  64) : NEG; \
  d2 = (lane + 128 < nv4) ? LDNT((bp) + lane + 128) : NEG; \
  d3 = (lane + 192 < nv4) ? LDNT((bp) + lane + 192) : NEG;

  vfloat4 a0, a1, a2, a3, b0, b1, b2, b3;
  const vfloat4* p1 = p0 + nv4;
  const vfloat4* p2 = p1 + nv4;
  const vfloat4* p3 = p2 + nv4;

  // prime: row r0
  LOADQ(a0, a1, a2, a3, p0);

  // row r0: prefetch r0+1, reduce a
  if (has1) { LOADQ(b0, b1, b2, b3, p1); }
  {
    float ot = extract_elem(a0, a1, a2, a3, t0);
    float cev = reduce_ce(a0, a1, a2, a3, ot);
    if (lane == 0) ce[r0] = cev;
  }
  if (!has1) return;

  // row r0+1: prefetch r0+2 into a, reduce b
  if (has2) { LOADQ(a0, a1, a2, a3, p2); }
  {
    float ot = extract_elem(b0, b1, b2, b3, t1);
    float cev = reduce_ce(b0, b1, b2, b3, ot);
    if (lane == 0) ce[r0 + 1] = cev;
  }
  if (!has2) return;

  // row r0+2: prefetch r0+3 into b, reduce a
  if (has3) { LOADQ(b0, b1, b2, b3, p3); }
  {
    float ot = extract_elem(a0, a1, a2, a3, t2);
    float cev = reduce_ce(a0, a1, a2, a3, ot);
    if (lane == 0) ce[r0 + 2] = cev;
  }
  if (!has3) return;

  // row r0+3: reduce b
  {
    float ot = extract_elem(b0, b1, b2, b3, t3);
    float cev = reduce_ce(b0, b1, b2, b3, ot);
    if (lane == 0) ce[r0 + 3] = cev;
  }
#undef LOADQ
}

// ---------------- selection + filtered mean (single block) ----------------

// Find descending-rank `rank` in packed 16384-bin hist H (8192 words),
// 1024 threads, g[1024] scratch. Out: sel[0]=bin, sel[1]=rank-within-bin.
__device__ void find_level_1024(uint32* H, uint32* g, uint32 rank, int tid,
                                volatile uint32* sel) {
  uint32 c = 0;
#pragma unroll
  for (int j = 0; j < 8; ++j) {
    uint32 w = H[8 * tid + j];
    c += (w & 0xFFFFu) + (w >> 16);
  }
  g[tid] = c;
  __syncthreads();
  for (int off = 1; off < 1024; off <<= 1) {  // inclusive suffix scan
    uint32 v = g[tid] + ((tid + off < 1024) ? g[tid + off] : 0u);
    __syncthreads();
    g[tid] = v;
    __syncthreads();
  }
  uint32 SG = (tid + 1 < 1024) ? g[tid + 1] : 0u;
  if (SG <= rank && rank < g[tid]) { sel[0] = (uint32)tid; sel[1] = rank - SG; }
  __syncthreads();
  if (tid == 0) {
    uint32 grp = sel[0], kg = sel[1], acc = 0;
    for (int b = 15; b >= 0; --b) {
      uint32 bin = grp * 16u + (uint32)b;
      uint32 w = H[bin >> 1];
      uint32 cc = (bin & 1u) ? (w >> 16) : (w & 0xFFFFu);
      if (kg < acc + cc) { sel[0] = bin; sel[1] = kg - acc; break; }
      acc += cc;
    }
  }
  __syncthreads();
}

__global__ __launch_bounds__(1024) void select_kernel(
    const float* __restrict__ ce, float* __restrict__ out, int N, int k) {
  __shared__ uint32 H[8192];     // packed 16384-bin hist (reused level 2)
  __shared__ uint32 Cand[8192];  // candidate bit patterns
  __shared__ uint32 g[1024];
  __shared__ uint32 sel[2];
  __shared__ uint32 ccnt;
  __shared__ uint32 cnt8[8];
  __shared__ double wsum[16];
  const int tid = (int)threadIdx.x;
  const int lane = tid & 63;
  const float4* ce4 = (const float4*)ce;
  const int N4 = N >> 2;  // N % 4 == 0

  if (tid == 0) ccnt = 0;
  if (tid < 8) cnt8[tid] = 0;
  for (int j = tid; j < 8192; j += 1024) H[j] = 0;
  __syncthreads();

  // ---- Pass 1: 16384-bin hist of key = u >> 17 (ce >= 0 -> key <= 16320) ----
  for (int i = tid; i < N4; i += 1024) {
    float4 x = ce4[i];
    uint32 k0 = __float_as_uint(x.x) >> 17;
    uint32 k1 = __float_as_uint(x.y) >> 17;
    uint32 k2 = __float_as_uint(x.z) >> 17;
    uint32 k3 = __float_as_uint(x.w) >> 17;
    atomicAdd(&H[k0 >> 1], (k0 & 1u) ? 0x10000u : 1u);
    atomicAdd(&H[k1 >> 1], (k1 & 1u) ? 0x10000u : 1u);
    atomicAdd(&H[k2 >> 1], (k2 & 1u) ? 0x10000u : 1u);
    atomicAdd(&H[k3 >> 1], (k3 & 1u) ? 0x10000u : 1u);
  }
  __syncthreads();
  find_level_1024(H, g, (uint32)k, tid, sel);
  const uint32 K = sel[0];
  const uint32 kr1 = sel[1];
  __syncthreads();

  // ---- Pass 2: sum key > K; ballot-collect key == K candidates ----
  double acc = 0.0;
  const int iters = (N4 + 1023) / 1024;
  for (int it = 0; it < iters; ++it) {   // uniform trip count for ballots
    int i = it * 1024 + tid;
    bool valid = (i < N4);
    float4 x = make_float4(0.f, 0.f, 0.f, 0.f);
    if (valid) x = ce4[i];
    float f[4] = {x.x, x.y, x.z, x.w};
#pragma unroll
    for (int j = 0; j < 4; ++j) {
      uint32 u = __float_as_uint(f[j]);
      uint32 key = u >> 17;
      if (valid && key > K) acc += (double)f[j];
      bool mine = valid && (key == K);
      unsigned long long mk = __ballot(mine);
      if (mk) {
        int src = (int)__ffsll(mk) - 1;
        uint32 base = 0;
        if (lane == src) base = atomicAdd(&ccnt, (uint32)__popcll(mk));
        base = (uint32)__shfl((int)base, src);
        if (mine) {
          uint32 p = base + (uint32)__popcll(mk & ((1ull << lane) - 1ull));
          if (p < 8192u) Cand[p] = u;
        }
      }
    }
  }
  __syncthreads();
  const uint32 c = (ccnt < 8192u) ? ccnt : 8192u;

  // ---- Level 2: hist over candidate bits 16..3 (14 bits) ----
  for (int j = tid; j < 8192; j += 1024) H[j] = 0;
  __syncthreads();
  for (uint32 j = (uint32)tid; j < c; j += 1024u) {
    uint32 k2 = (Cand[j] >> 3) & 0x3FFFu;
    atomicAdd(&H[k2 >> 1], (k2 & 1u) ? 0x10000u : 1u);
  }
  __syncthreads();
  find_level_1024(H, g, kr1, tid, sel);
  const uint32 B2 = sel[0];
  const uint32 kr2 = sel[1];
  __syncthreads();

  const uint32 lam_hi = (K << 17) | (B2 << 3);

  // ---- Level 3: 8 bins over bits 2..0 ----
  for (uint32 j = (uint32)tid; j < c; j += 1024u) {
    uint32 u = Cand[j];
    if ((u >> 3) == (lam_hi >> 3)) atomicAdd(&cnt8[u & 7u], 1u);
  }
  __syncthreads();
  if (tid == 0) {
    uint32 kg = kr2, a2 = 0;
    for (int b = 7; b >= 0; --b) {
      uint32 cc = cnt8[b];
      if (kg < a2 + cc) { sel[0] = lam_hi | (uint32)b; break; }
      a2 += cc;
    }
  }
  __syncthreads();
  const uint32 lam = sel[0];

  // ---- Add candidates >= lam (ties kept: matches where(ce<lam,0,ce)) ----
  for (uint32 j = (uint32)tid; j < c; j += 1024u) {
    uint32 u = Cand[j];
    if (u >= lam) acc += (double)__uint_as_float(u);
  }

  // ---- Reduce and write mean over all N ----
#pragma unroll
  for (int off = 1; off < 64; off <<= 1) acc += __shfl_xor(acc, off);
  if ((tid & 63) == 0) wsum[tid >> 6] = acc;
  __syncthreads();
  if (tid == 0) {
    double tsum = 0.0;
    for (int i = 0; i < 16; ++i) tsum += wsum[i];
    out[0] = (float)(tsum / (double)N);
  }
}

extern "C" void kernel_launch(void* const* d_in, const int* in_sizes, int n_in,
                              void* d_out, int out_size, void* d_ws, size_t ws_size,
                              hipStream_t stream) {
  const float* logits = (const float*)d_in[0];
  const int* target = (const int*)d_in[1];
  float* out = (float*)d_out;

  const int N = in_sizes[1];            // 32768
  const int C = in_sizes[0] / N;        // 1000
  const int k = (int)((double)N * 0.3); // 9830

  float* ce = (float*)d_ws;

  // K1: 4 rows per wave, 16 rows per 256-thread block.
  int nblk = (N + 15) / 16;  // 2048
  ce_kernel<<<nblk, 256, 0, stream>>>(logits, target, ce, N, C);

  // K2: single block: hist + select + filtered mean. No memset needed.
  select_kernel<<<1, 1024, 0, stream>>>(ce, out, N, k);
}